// Round 1
// baseline (262.631 us; speedup 1.0000x reference)
//
#include <hip/hip_runtime.h>
#include <stdint.h>

typedef int v4i  __attribute__((ext_vector_type(4)));
typedef int v16i __attribute__((ext_vector_type(16)));

// ---------------------------------------------------------------------------
// Kernel 1: quantize activations fp32 -> int8, plus per-row sums.
// One block (256 threads) per row of K elements (K multiple of 1024).
// q = clip(rint(x/s) + zp, -128, 127); sum_x[row] = sum_k q
// ---------------------------------------------------------------------------
__global__ void quant_x_kernel(const float* __restrict__ x,
                               int8_t* __restrict__ xq,
                               int* __restrict__ sum_x,
                               const float* __restrict__ p_scale,
                               const int* __restrict__ p_zp,
                               int K) {
    const int row = blockIdx.x;
    const int t = threadIdx.x;
    const float s = p_scale[0];
    const float zpf = (float)p_zp[0];
    const float* xr = x + (size_t)row * K;
    int8_t* qr = xq + (size_t)row * K;
    int lsum = 0;
    const int nchunk = K >> 10;              // each pass covers 256 thr * 4 elems
    for (int i = 0; i < nchunk; ++i) {
        const int idx = (i << 10) + (t << 2);
        const float4 v = *reinterpret_cast<const float4*>(xr + idx);
        // division (not mul-by-reciprocal) to match jnp rounding; rintf = half-to-even
        const float f0 = fminf(fmaxf(rintf(v.x / s) + zpf, -128.f), 127.f);
        const float f1 = fminf(fmaxf(rintf(v.y / s) + zpf, -128.f), 127.f);
        const float f2 = fminf(fmaxf(rintf(v.z / s) + zpf, -128.f), 127.f);
        const float f3 = fminf(fmaxf(rintf(v.w / s) + zpf, -128.f), 127.f);
        const int i0 = (int)f0, i1 = (int)f1, i2 = (int)f2, i3 = (int)f3;
        lsum += i0 + i1 + i2 + i3;
        const unsigned pk = (unsigned)(i0 & 255) | ((unsigned)(i1 & 255) << 8) |
                            ((unsigned)(i2 & 255) << 16) | ((unsigned)(i3 & 255) << 24);
        *reinterpret_cast<unsigned*>(qr + idx) = pk;
    }
    __shared__ int wsum[4];
    #pragma unroll
    for (int off = 32; off > 0; off >>= 1) lsum += __shfl_down(lsum, off);
    if ((t & 63) == 0) wsum[t >> 6] = lsum;
    __syncthreads();
    if (t == 0) sum_x[row] = wsum[0] + wsum[1] + wsum[2] + wsum[3];
}

// ---------------------------------------------------------------------------
// Kernel 2: pack weight int32 (int8-valued) -> int8, plus per-row sums.
// ---------------------------------------------------------------------------
__global__ void quant_w_kernel(const int* __restrict__ w,
                               int8_t* __restrict__ wq,
                               int* __restrict__ sum_w,
                               int K) {
    const int row = blockIdx.x;
    const int t = threadIdx.x;
    const int* wr_ = w + (size_t)row * K;
    int8_t* qr = wq + (size_t)row * K;
    int lsum = 0;
    const int nchunk = K >> 10;
    for (int i = 0; i < nchunk; ++i) {
        const int idx = (i << 10) + (t << 2);
        const int4 v = *reinterpret_cast<const int4*>(wr_ + idx);
        lsum += v.x + v.y + v.z + v.w;
        const unsigned pk = (unsigned)(v.x & 255) | ((unsigned)(v.y & 255) << 8) |
                            ((unsigned)(v.z & 255) << 16) | ((unsigned)(v.w & 255) << 24);
        *reinterpret_cast<unsigned*>(qr + idx) = pk;
    }
    __shared__ int wsum[4];
    #pragma unroll
    for (int off = 32; off > 0; off >>= 1) lsum += __shfl_down(lsum, off);
    if ((t & 63) == 0) wsum[t >> 6] = lsum;
    __syncthreads();
    if (t == 0) sum_w[row] = wsum[0] + wsum[1] + wsum[2] + wsum[3];
}

// ---------------------------------------------------------------------------
// Kernel 3: int8 GEMM, C[m][n] = sum_k xq[m][k]*wq[n][k], with zp-correction
// epilogue. 128x128 block tile, BK=64, 4 waves, each wave 64x64 output via
// 2x2 frags of v_mfma_i32_32x32x32_i8.
//
// LDS is FRAGMENT-MAJOR: each 32(rows)x32(k-bytes) fragment is stored as 64
// contiguous 16B chunks indexed by lane id -> ds_read_b128 at lane*16 and the
// staging ds_write_b128 pattern are both exactly bank-uniform (conflict-free).
// Register-prefetch double buffer, one __syncthreads per K-iteration.
// ---------------------------------------------------------------------------
#define BM 128
#define BN 128
#define BK 64

__global__ __launch_bounds__(256, 2)
void gemm_i8_kernel(const int8_t* __restrict__ xq,
                    const int8_t* __restrict__ wq,
                    const int* __restrict__ sum_x,
                    const int* __restrict__ sum_w,
                    const float* __restrict__ bias,
                    float* __restrict__ out,
                    const float* __restrict__ p_sa,
                    const int* __restrict__ p_zpa,
                    const float* __restrict__ p_sw,
                    const int* __restrict__ p_wzp,
                    int M, int N, int K) {
    __shared__ v4i ldsA[2][512];   // 2 buf * 8 frag-blocks * 64 chunks
    __shared__ v4i ldsB[2][512];

    const int tid = threadIdx.x;
    const int lane = tid & 63;
    const int wid = tid >> 6;
    const int wr = wid >> 1;           // wave row 0..1  (64 rows each)
    const int wc = wid & 1;            // wave col 0..1  (64 cols each)
    const int m0 = blockIdx.y * BM;
    const int n0 = blockIdx.x * BN;

    // staging geometry: thread t handles 16B chunks (srow, sq) and (srow+64, sq)
    // chunk (row,q) holds bytes [row][q*16 .. q*16+16) of the 128x64 tile.
    // fragment-major LDS position: fb = (q>>1)*4 + row>>5 ; lane = (q&1)*32 + (row&31)
    const int srow = tid >> 2;
    const int sq = tid & 3;
    const int lc = ((sq >> 1) * 4 + (srow >> 5)) * 64 + (sq & 1) * 32 + (srow & 31);
    const int8_t* gA = xq + (size_t)(m0 + srow) * K + sq * 16;
    const int8_t* gB = wq + (size_t)(n0 + srow) * K + sq * 16;
    const size_t rstride = (size_t)64 * K;

    v16i acc[2][2] = {};
    v4i pa0, pa1, pb0, pb1;

    const int NT = K / BK;

    // prologue: stage tile 0
    pa0 = *reinterpret_cast<const v4i*>(gA);
    pa1 = *reinterpret_cast<const v4i*>(gA + rstride);
    pb0 = *reinterpret_cast<const v4i*>(gB);
    pb1 = *reinterpret_cast<const v4i*>(gB + rstride);
    ldsA[0][lc] = pa0; ldsA[0][lc + 128] = pa1;
    ldsB[0][lc] = pb0; ldsB[0][lc + 128] = pb1;

    int cur = 0;
    for (int t = 0; t < NT; ++t) {
        __syncthreads();   // buf[cur] ready; all readers of buf[cur^1] done
        if (t + 1 < NT) {
            const int koff = (t + 1) * BK;
            pa0 = *reinterpret_cast<const v4i*>(gA + koff);
            pa1 = *reinterpret_cast<const v4i*>(gA + rstride + koff);
            pb0 = *reinterpret_cast<const v4i*>(gB + koff);
            pb1 = *reinterpret_cast<const v4i*>(gB + rstride + koff);
        }
        #pragma unroll
        for (int ks = 0; ks < 2; ++ks) {
            const v4i a0 = ldsA[cur][(ks * 4 + wr * 2 + 0) * 64 + lane];
            const v4i a1 = ldsA[cur][(ks * 4 + wr * 2 + 1) * 64 + lane];
            const v4i b0 = ldsB[cur][(ks * 4 + wc * 2 + 0) * 64 + lane];
            const v4i b1 = ldsB[cur][(ks * 4 + wc * 2 + 1) * 64 + lane];
            acc[0][0] = __builtin_amdgcn_mfma_i32_32x32x32_i8(a0, b0, acc[0][0], 0, 0, 0);
            acc[0][1] = __builtin_amdgcn_mfma_i32_32x32x32_i8(a0, b1, acc[0][1], 0, 0, 0);
            acc[1][0] = __builtin_amdgcn_mfma_i32_32x32x32_i8(a1, b0, acc[1][0], 0, 0, 0);
            acc[1][1] = __builtin_amdgcn_mfma_i32_32x32x32_i8(a1, b1, acc[1][1], 0, 0, 0);
        }
        if (t + 1 < NT) {
            const int nb = cur ^ 1;
            ldsA[nb][lc] = pa0; ldsA[nb][lc + 128] = pa1;
            ldsB[nb][lc] = pb0; ldsB[nb][lc + 128] = pb1;
        }
        cur ^= 1;
    }

    // epilogue: y = (acc - wzp*sum_x[m] - zp*sum_w[n] + K*zp*wzp) * (sa*sw) + bias[n]
    const float stot = p_sa[0] * p_sw[0];
    const int zpa = p_zpa[0];
    const int wzp = p_wzp[0];
    const int kzz = K * zpa * wzp;
    const int coll = lane & 31;
    const int rhi = (lane >> 5) * 4;

    #pragma unroll
    for (int nf = 0; nf < 2; ++nf) {
        const int cg = n0 + wc * 64 + nf * 32 + coll;
        const int sw = sum_w[cg];
        const float bb = bias[cg];
        #pragma unroll
        for (int mf = 0; mf < 2; ++mf) {
            const int rbase = m0 + wr * 64 + mf * 32 + rhi;
            #pragma unroll
            for (int r = 0; r < 16; ++r) {
                const int rowg = rbase + (r & 3) + 8 * (r >> 2);
                const int iv = acc[mf][nf][r] - wzp * sum_x[rowg] - zpa * sw + kzz;
                out[(size_t)rowg * N + cg] = (float)iv * stot + bb;
            }
        }
    }
}

// ---------------------------------------------------------------------------
extern "C" void kernel_launch(void* const* d_in, const int* in_sizes, int n_in,
                              void* d_out, int out_size, void* d_ws, size_t ws_size,
                              hipStream_t stream) {
    const float* x     = (const float*)d_in[0];
    const int*   w     = (const int*)d_in[1];
    const float* bias  = (const float*)d_in[2];
    const float* p_sa  = (const float*)d_in[3];
    const int*   p_zpa = (const int*)d_in[4];
    const float* p_sw  = (const float*)d_in[5];
    const int*   p_wzp = (const int*)d_in[6];

    const int N = in_sizes[2];             // OUT
    const int K = in_sizes[1] / N;         // IN
    const int M = in_sizes[0] / K;         // B*S

    // workspace layout: xq[M*K] i8 | wq[N*K] i8 | sum_x[M] i32 | sum_w[N] i32
    int8_t* xq = (int8_t*)d_ws;
    int8_t* wq = xq + (size_t)M * K;
    int* sum_x = (int*)(wq + (size_t)N * K);
    int* sum_w = sum_x + M;

    quant_x_kernel<<<M, 256, 0, stream>>>(x, xq, sum_x, p_sa, p_zpa, K);
    quant_w_kernel<<<N, 256, 0, stream>>>(w, wq, sum_w, K);

    dim3 grid(N / BN, M / BM);
    gemm_i8_kernel<<<grid, 256, 0, stream>>>(xq, wq, sum_x, sum_w, bias,
                                             (float*)d_out, p_sa, p_zpa, p_sw, p_wzp,
                                             M, N, K);
}